// Round 7
// baseline (725.179 us; speedup 1.0000x reference)
//
#include <hip/hip_runtime.h>

// ---------------------------------------------------------------------------
// StandAttention: out = softmax_causal((xWq+bq)(xWk+bk)^T / sqrt(d)) (xWv+bv) Wo + bo
// b=4, s=4096, d=1024. fp32 in/out, bf16 MFMA compute.
//
// R13 changes vs R12 (R12: 508us; 7 schedule variants all pinned at ~880 TF/
// busy-CU -> schedule lever exhausted within observability; pivot to WORK
// REMOVAL: fuse softmax into scores-epilogue + PV staging):
//  - gemm8ph MODE1 epilogue: per-(row,tile) softmax partials (pmax, sumexp)
//    computed from the bf16-ROUNDED values (bit-identical basis to what PV
//    reads) with causal masking on diagonal tiles. 2 small LDS arrays + wave
//    shfl reduction; writes 2MB f32 scratch.
//  - sm_combine: 16K-row kernel folding partials into per-row M, 1/L (~4us).
//  - gemm_pvf: PV stages A (attn) via REGISTERS with in-flight
//    P = exp(s - M)*Linv + causal mask, ds_write to the same linear LDS dest
//    (read-side swizzle unchanged). A-load issued 2 K-tiles ahead; queue
//    ledger: entering tile t = [A(cons@t), B(t+1)x2]; vmcnt(3) publishes
//    B(t+1); writer's lgkm(0) drains the ds_write before the publish barrier.
//  - softmax_causal kernel + fringe-zeroing DELETED (~40us + 200MB traffic).
//  - GEMM cores otherwise frozen (clean attribution).
// ---------------------------------------------------------------------------

typedef unsigned short u16;
typedef __attribute__((ext_vector_type(4))) unsigned short u16x4;
typedef __attribute__((ext_vector_type(8))) unsigned short u16x8;
typedef __attribute__((ext_vector_type(8))) __bf16 bf16x8;
typedef __attribute__((ext_vector_type(4))) float f32x4;

typedef const __attribute__((address_space(1))) void* as1cp;
typedef __attribute__((address_space(3))) void* as3p;

#define SBAR() __builtin_amdgcn_s_barrier()
#define SPIN() __builtin_amdgcn_sched_barrier(0)

struct GemmPtrs {
  const u16* A[4];
  const u16* B[4];
  const float* bias[4];
  void* C[4];
};
struct TransPtrs {
  const void* in[4];
  u16* out[4];
};

__device__ __forceinline__ u16 f2bf(float f) {
  union { float f; unsigned int i; } c; c.f = f;
  unsigned int r = c.i + 0x7fffu + ((c.i >> 16) & 1u);   // RNE
  return (u16)(r >> 16);
}
__device__ __forceinline__ float bf2f(u16 u) {
  union { unsigned int i; float f; } c; c.i = ((unsigned int)u) << 16;
  return c.f;
}

// ---------------- cast fp32 -> bf16 (vectorized) ----------------
__global__ __launch_bounds__(256) void cast_f32_bf16(const float* __restrict__ in,
                                                     u16* __restrict__ out, int n4) {
  int i = blockIdx.x * blockDim.x + threadIdx.x;
  if (i >= n4) return;
  float4 v = ((const float4*)in)[i];
  u16x4 u;
  u.x = f2bf(v.x); u.y = f2bf(v.y); u.z = f2bf(v.z); u.w = f2bf(v.w);
  ((u16x4*)out)[i] = u;
}

// ---------------- LDS-tiled transpose (-> bf16), batched by z ----------------
template <bool IN_F32>
__global__ __launch_bounds__(256) void transpose_to_bf16(TransPtrs tp, int R, int C) {
  __shared__ u16 t[32][34];
  int z = blockIdx.z;
  int tx = threadIdx.x, ty = threadIdx.y;
  int c0 = blockIdx.x * 32, r0 = blockIdx.y * 32;
#pragma unroll
  for (int dy = 0; dy < 4; ++dy) {
    int r = r0 + ty + dy * 8;
    int c = c0 + tx;
    u16 hv;
    if (IN_F32) hv = f2bf(((const float*)tp.in[z])[(size_t)r * C + c]);
    else        hv = ((const u16*)tp.in[z])[(size_t)r * C + c];
    t[ty + dy * 8][tx] = hv;
  }
  __syncthreads();
  u16* op = tp.out[z];
#pragma unroll
  for (int dy = 0; dy < 4; ++dy) {
    int a = ty + dy * 8;
    op[(size_t)(c0 + a) * R + r0 + tx] = t[tx][a];
  }
}

// ---------------- combine per-tile softmax partials -> per-row M, 1/L -------
__global__ __launch_bounds__(256) void sm_combine(const float* __restrict__ gM,
                                                  const float* __restrict__ gS,
                                                  float* __restrict__ Mrow,
                                                  float* __restrict__ Linv) {
  int r = blockIdx.x * 256 + threadIdx.x;     // 0..16383
  int z = r >> 12, row = r & 4095;
  int nb = (row >> 8) + 1;
  float M = -3.0e38f;
  for (int cb = 0; cb < nb; ++cb)
    M = fmaxf(M, gM[(((z * 16 + cb) << 12)) + row]);
  float L = 0.f;
  for (int cb = 0; cb < nb; ++cb) {
    float pm = gM[(((z * 16 + cb) << 12)) + row];
    L += gS[(((z * 16 + cb) << 12)) + row] * __expf(pm - M);
  }
  Mrow[(z << 12) + row] = M;
  Linv[(z << 12) + row] = 1.0f / L;
}

// ---------------------------------------------------------------------------
// gemm8ph: 256x256 tile, BK=32, 8 waves (2M x 4N), per-wave 128x64 out.
// Ring-3 LDS. Per K-tile: 2 phases {read frags | stage half of t+2 | SBAR |
// lgkm(0) | 16 MFMA | SBAR}; vmcnt(4) once per K-tile.
// MODE 0: q/k/v proj (3 slots)  MODE 1: scores (3|2 slots) + softmax partials
// MODE 3: out-projection (1 slot)
// ---------------------------------------------------------------------------
template <int MODE, bool OUT_BF16, bool HAS_BIAS>
__global__ __launch_bounds__(512, 2) void gemm8ph(GemmPtrs p, int N, float cscale,
                                                  float* gM, float* gS) {
  __shared__ __align__(16) u16 As[3][8192];   // ring x 256 rows x 32 k
  __shared__ __align__(16) u16 Bs[3][8192];
  __shared__ __align__(16) float smax[1024];  // [256 rows][4 n-waves]
  __shared__ __align__(16) float ssum[1024];
  const int b = blockIdx.x;
  const int tid = threadIdx.x, lane = tid & 63, wv = tid >> 6;
  const int wm = (wv >> 2) << 7, wn = (wv & 3) << 6;
  const int lrow = lane & 15, lquad = lane >> 4;
  const int xs = (lquad ^ ((lrow >> 1) & 3)) << 3;
  const int aoff0 = (wm + lrow) * 32 + xs;
  const int boff0 = (wn + lrow) * 32 + xs;
  // stage src pre-swizzle: LDS[r][c] = G[r][c ^ ((r>>1)&3)]  (0 conflicts)
  const int soff = (tid >> 2) * 1024 + (((tid & 3) ^ ((tid >> 3) & 3)) << 3);
  const int x = b & 7, u = b >> 3;            // XCD, index-on-XCD
  const int nslot = (MODE == 1) ? (u < 4 ? 3 : 2) : (MODE == 0 ? 3 : 1);

  struct TP { const u16* A; const u16* B; int tm, tn, z; };
  auto tileOf = [&](int s) {
    TP t;
    if (MODE == 0) {
      int i = x * 32 + u;                 // 8-row band per XCD, reused over 3 mats
      t.z = s; t.tm = (i >> 2) << 8; t.tn = (i & 3) << 8;
    } else if (MODE == 1) {
      int g = x * 68 + s * 32 + u;        // per-XCD contiguous tri range
      t.z = g / 136; int L = g - t.z * 136;
      int i = (int)((__fsqrt_rn(8.f * (float)L + 1.f) - 1.f) * 0.5f);
      while ((i + 1) * (i + 2) / 2 <= L) ++i;
      while (i * (i + 1) / 2 > L) --i;
      t.tm = i << 8; t.tn = (L - ((i * (i + 1)) >> 1)) << 8;
    } else {
      int i = x * 32 + u;
      t.z = 0; t.tm = (i >> 2) << 8; t.tn = (i & 3) << 8;
    }
    t.A = p.A[t.z] + (size_t)t.tm * 1024;
    t.B = p.B[t.z] + (size_t)t.tn * 1024;
    return t;
  };

  // staging cursor (2 K-tiles ahead of compute)
  const u16* gA; const u16* gB; int stk = 0, sslot = 0;
  {
    TP t0 = tileOf(0);
    gA = t0.A + soff; gB = t0.B + soff;
  }
  auto adv = [&]() {
    gA += 32; gB += 32;
    if (++stk == 32) {
      stk = 0;
      if (++sslot < nslot) {
        TP t = tileOf(sslot);
        gA = t.A + soff; gB = t.B + soff;
      }
    }
  };
  auto stgA = [&](int s) __attribute__((always_inline)) {
    __builtin_amdgcn_global_load_lds((as1cp)gA, (as3p)(As[s] + wv * 512), 16, 0, 0);
    __builtin_amdgcn_global_load_lds((as1cp)(gA + 131072), (as3p)(As[s] + 4096 + wv * 512), 16, 0, 0);
  };
  auto stgB = [&](int s) __attribute__((always_inline)) {
    __builtin_amdgcn_global_load_lds((as1cp)gB, (as3p)(Bs[s] + wv * 512), 16, 0, 0);
    __builtin_amdgcn_global_load_lds((as1cp)(gB + 131072), (as3p)(Bs[s] + 4096 + wv * 512), 16, 0, 0);
    adv();
  };

  f32x4 acc[8][4];
#pragma unroll
  for (int i = 0; i < 8; ++i)
#pragma unroll
    for (int j = 0; j < 4; ++j) acc[i][j] = (f32x4){0.f, 0.f, 0.f, 0.f};

  auto epi = [&](int cs2) {
    TP t = tileOf(cs2);
    if constexpr (MODE == 1) {
      // ---- softmax partials over this tile's 256 cols (bf16-rounded basis)
      const bool diag = (t.tm == t.tn);
      const int wnidx = wv & 3;
#pragma unroll
      for (int m = 0; m < 8; ++m)
#pragma unroll
        for (int r = 0; r < 4; ++r) {
          int rl = wm + m * 16 + lquad * 4 + r;
          float mx = -3.0e38f;
#pragma unroll
          for (int n = 0; n < 4; ++n) {
            float vb = bf2f(f2bf(acc[m][n][r] * cscale));
            int cl = wn + n * 16 + lrow;
            if (diag && cl > rl) vb = -3.0e38f;
            mx = fmaxf(mx, vb);
          }
          mx = fmaxf(mx, __shfl_xor(mx, 1, 64));
          mx = fmaxf(mx, __shfl_xor(mx, 2, 64));
          mx = fmaxf(mx, __shfl_xor(mx, 4, 64));
          mx = fmaxf(mx, __shfl_xor(mx, 8, 64));
          if (lrow == 0) smax[rl * 4 + wnidx] = mx;
        }
      SBAR();
#pragma unroll
      for (int m = 0; m < 8; ++m)
#pragma unroll
        for (int r = 0; r < 4; ++r) {
          int rl = wm + m * 16 + lquad * 4 + r;
          f32x4 m4 = *(const f32x4*)&smax[rl * 4];
          float Mt = fmaxf(fmaxf(m4[0], m4[1]), fmaxf(m4[2], m4[3]));
          float sm = 0.f;
#pragma unroll
          for (int n = 0; n < 4; ++n) {
            float vb = bf2f(f2bf(acc[m][n][r] * cscale));
            int cl = wn + n * 16 + lrow;
            if (diag && cl > rl) vb = -3.0e38f;   // exp -> 0
            sm += __expf(vb - Mt);
          }
          sm += __shfl_xor(sm, 1, 64); sm += __shfl_xor(sm, 2, 64);
          sm += __shfl_xor(sm, 4, 64); sm += __shfl_xor(sm, 8, 64);
          if (lrow == 0) ssum[rl * 4 + wnidx] = sm;
        }
      SBAR();
      if ((wv & 3) == 0) {                 // waves 0,4 finalize 128 rows each
#pragma unroll
        for (int h = 0; h < 2; ++h) {
          int rl = wm + h * 64 + lane;
          f32x4 m4 = *(const f32x4*)&smax[rl * 4];
          float Mt = fmaxf(fmaxf(m4[0], m4[1]), fmaxf(m4[2], m4[3]));
          f32x4 s4 = *(const f32x4*)&ssum[rl * 4];
          float L = (s4[0] + s4[1]) + (s4[2] + s4[3]);
          int row_abs = t.tm + rl;
          int cb = t.tn >> 8;
          gM[((t.z * 16 + cb) << 12) + row_abs] = Mt;
          gS[((t.z * 16 + cb) << 12) + row_abs] = L;
        }
      }
      SBAR();
    }
    float bvv[4] = {0.f, 0.f, 0.f, 0.f};
    if constexpr (HAS_BIAS) {
#pragma unroll
      for (int n = 0; n < 4; ++n) bvv[n] = p.bias[t.z][t.tn + wn + n * 16 + lrow];
    }
#pragma unroll
    for (int m = 0; m < 8; ++m)
#pragma unroll
      for (int r = 0; r < 4; ++r) {
        size_t row = (size_t)(t.tm + wm + m * 16 + lquad * 4 + r);
#pragma unroll
        for (int n = 0; n < 4; ++n) {
          int col = t.tn + wn + n * 16 + lrow;
          float vvv = acc[m][n][r] * cscale + bvv[n];
          if (OUT_BF16) ((u16*)p.C[t.z])[row * N + col] = f2bf(vvv);
          else          ((float*)p.C[t.z])[row * N + col] = vvv;
        }
      }
#pragma unroll
    for (int m2 = 0; m2 < 8; ++m2)
#pragma unroll
      for (int n2 = 0; n2 < 4; ++n2) acc[m2][n2] = (f32x4){0.f, 0.f, 0.f, 0.f};
  };

  // prologue: stage tiles 0,1 -> slots 0,1; publish tile 0 (tile 1 in flight)
  stgA(0); stgB(0);
  stgA(1); stgB(1);
  asm volatile("s_waitcnt vmcnt(4)");
  SBAR();
  SPIN();

  const int T = nslot * 32;
  int cs = 0, c = 0;
  for (int t = 0; t < T; ++t) {
    const int s = (c >= 1) ? c - 1 : 2;       // (c+2)%3
    const bool stg = (t + 2) < T;
    bf16x8 af[4], bf[4];
    // ---------------- phase 0: m0-3 x n0-3 ----------------
#pragma unroll
    for (int m = 0; m < 4; ++m) af[m] = *(const bf16x8*)&As[c][aoff0 + m * 512];
#pragma unroll
    for (int n = 0; n < 4; ++n) bf[n] = *(const bf16x8*)&Bs[c][boff0 + n * 512];
    if (stg) stgA(s);
    SPIN();
    SBAR();
    asm volatile("s_waitcnt lgkmcnt(0)");
    SPIN();
    __builtin_amdgcn_s_setprio(1);
#pragma unroll
    for (int m = 0; m < 4; ++m)
#pragma unroll
      for (int n = 0; n < 4; ++n)
        acc[m][n] = __builtin_amdgcn_mfma_f32_16x16x32_bf16(af[m], bf[n], acc[m][n], 0, 0, 0);
    __builtin_amdgcn_s_setprio(0);
    SPIN();
    SBAR();
    // ---------------- phase 1: m4-7 x n0-3 (B held) ----------------
#pragma unroll
    for (int m = 0; m < 4; ++m) af[m] = *(const bf16x8*)&As[c][aoff0 + 2048 + m * 512];
    if (stg) stgB(s);
    SPIN();
    if (stg)               asm volatile("s_waitcnt vmcnt(4)");
    else if (t + 1 < T)    asm volatile("s_waitcnt vmcnt(0)");
    SBAR();
    asm volatile("s_waitcnt lgkmcnt(0)");
    SPIN();
    __builtin_amdgcn_s_setprio(1);
#pragma unroll
    for (int m = 0; m < 4; ++m)
#pragma unroll
      for (int n = 0; n < 4; ++n)
        acc[4 + m][n] = __builtin_amdgcn_mfma_f32_16x16x32_bf16(af[m], bf[n], acc[4 + m][n], 0, 0, 0);
    __builtin_amdgcn_s_setprio(0);
    SPIN();
    SBAR();
    if (((t + 1) & 31) == 0) { SPIN(); epi(cs); ++cs; }
    if (++c == 3) c = 0;
  }
}

// ---------------------------------------------------------------------------
// gemm_pvf: ctx[tile 128x256] = P[128,K] @ vT[256,K]^T with P computed in
// flight: P = exp(s - M[row]) * Linv[row], causal-masked on diagonal band.
// K=128(i+1) causal, BK=32, pair (i,31-i) -> 132 K-tiles/block. Ring-3 LDS.
// A staged via registers (load 2 tiles ahead) + transform + ds_write (linear
// dest = same layout global_load_lds produced; read swizzle unchanged).
// ---------------------------------------------------------------------------
__global__ __launch_bounds__(512, 2) void gemm_pvf(GemmPtrs p,
                                                   const float* __restrict__ Mrow,
                                                   const float* __restrict__ Linv) {
  __shared__ __align__(16) u16 As[3][4096];   // 128 x 32
  __shared__ __align__(16) u16 Bs[3][8192];   // 256 x 32
  const int b = blockIdx.x;
  const int tid = threadIdx.x, lane = tid & 63, wv = tid >> 6;
  const int wm = (wv >> 2) << 6, wn = (wv & 3) << 6;
  const int lrow = lane & 15, lquad = lane >> 4;
  const int xs = (lquad ^ ((lrow >> 1) & 3)) << 3;
  const int aoff0 = (wm + lrow) * 32 + xs;
  const int boff0 = (wn + lrow) * 32 + xs;
  const int jsw = (((tid & 3) ^ ((tid >> 3) & 3)) << 3);      // A col pre-swizzle
  const int soffB = (tid >> 2) * 4096 + jsw;                   // B src offset
  const int x = b & 7, u = b >> 3;
  const int P = x * 32 + u;                   // n fastest within XCD (A reuse x4)
  const int z = P >> 6, j = (P >> 2) & 15, n4 = P & 3;
  const int i1 = j, i2 = 31 - j;
  const int tn = n4 << 8;
  const int T1 = (i1 + 1) * 4;
  const int T = 132;
  const int T2 = T - T1;                      // (i2+1)*4
  const u16* Abase = p.A[z];
  const u16* Bbase = p.B[z] + (size_t)tn * 4096;

  const int rloc = tid >> 2;                  // A row within tile (0..127)
  const int ra1 = (i1 << 7) + rloc, ra2 = (i2 << 7) + rloc;
  const float M1 = Mrow[(z << 12) + ra1], L1i = Linv[(z << 12) + ra1];
  const float M2 = Mrow[(z << 12) + ra2], L2i = Linv[(z << 12) + ra2];

  const u16* gA = Abase + (size_t)ra1 * 4096 + jsw;           // per-thread A ptr
  const u16* gB = Bbase + soffB;
  int stk = 0;
  auto adv = [&]() {
    gA += 32; gB += 32;
    if (++stk == T1) {
      gA = Abase + (size_t)ra2 * 4096 + jsw;
      gB = Bbase + soffB;
    }
  };
  auto stgB = [&](int s) __attribute__((always_inline)) {
    __builtin_amdgcn_global_load_lds((as1cp)gB, (as3p)(Bs[s] + wv * 512), 16, 0, 0);
    __builtin_amdgcn_global_load_lds((as1cp)(gB + 524288), (as3p)(Bs[s] + 4096 + wv * 512), 16, 0, 0);
  };

  // transform k-tile kt's A data -> LDS slot
  auto xform = [&](int kt, int slot, u16x8 a8) __attribute__((always_inline)) {
    const bool s2 = (kt >= T1);
    const int klocal = s2 ? kt - T1 : kt;
    const int Tseg = s2 ? T2 : T1;
    const float M = s2 ? M2 : M1;
    const float Li = s2 ? L2i : L1i;
    const int rabs = s2 ? ra2 : ra1;
    const int jb = klocal * 32 + jsw;
    const bool dia = (klocal >= Tseg - 4);
    u16x8 o;
#pragma unroll
    for (int e = 0; e < 8; ++e) {
      float s = bf2f(a8[e]);
      float pe = __expf(s - M) * Li;
      if (dia && (jb + e > rabs)) pe = 0.f;
      o[e] = f2bf(pe);
    }
    *(u16x8*)(As[slot] + tid * 8) = o;
  };

  f32x4 acc[4][4];
#pragma unroll
  for (int i = 0; i < 4; ++i)
#pragma unroll
    for (int jj = 0; jj < 4; ++jj) acc[i][jj] = (f32x4){0.f, 0.f, 0.f, 0.f};

  auto epi = [&](int s) {
    int tm = (s ? i2 : i1) << 7;
#pragma unroll
    for (int m = 0; m < 4; ++m)
#pragma unroll
      for (int r = 0; r < 4; ++r) {
        size_t row = (size_t)(tm + wm + m * 16 + lquad * 4 + r);
#pragma unroll
        for (int n = 0; n < 4; ++n) {
          int col = tn + wn + n * 16 + lrow;
          ((u16*)p.C[z])[row * 1024 + col] = f2bf(acc[m][n][r]);
        }
      }
#pragma unroll
    for (int m2 = 0; m2 < 4; ++m2)
#pragma unroll
      for (int n2 = 0; n2 < 4; ++n2) acc[m2][n2] = (f32x4){0.f, 0.f, 0.f, 0.f};
  };

  // ---- prologue: queue order per tile is [A-plain][B x2] ----
  u16x8 aregP;
  {
    u16x8 a0 = *(const u16x8*)gA;            // k0 data
    stgB(0); adv();                          // queue [A0, B0, B0]
    xform(0, 0, a0);                         // compiler waits A0 (vmcnt(2))
    aregP = *(const u16x8*)gA;               // k1 data
    stgB(1); adv();                          // queue [B0,B0, A1, B1,B1]
    SPIN();
    asm volatile("s_waitcnt vmcnt(3)");      // retire B0x2 -> slot0 B ready
    SBAR();
    SPIN();
  }

  int c = 0;
  for (int t = 0; t < T; ++t) {
    const int cnext = (c == 2) ? 0 : c + 1;
    const int cstage = (c >= 1) ? c - 1 : 2;  // (c+2)%3
    bf16x8 af[4], bf[4];
#pragma unroll
    for (int m = 0; m < 4; ++m) af[m] = *(const bf16x8*)&As[c][aoff0 + m * 512];
#pragma unroll
    for (int n = 0; n < 4; ++n) bf[n] = *(const bf16x8*)&Bs[c][boff0 + n * 512];
    if (t + 1 < T) xform(t + 1, cnext, aregP);  // uses A issued @ t-1
    if (t + 2 < T) {
      aregP = *(const u16x8*)gA;                // A for k-tile t+2
      SPIN();
      stgB(cstage);                             // B for k-tile t+2
      adv();
    }
    SPIN();
    if (t + 2 < T)      asm volatile("s_waitcnt vmcnt(3)");  // B(t+1) landed
    else if (t + 1 < T) asm volatile("s_waitcnt vmcnt(0)");
    SBAR();
    asm volatile("s_waitcnt lgkmcnt(0)");      // own frag reads + ds_write done
    SPIN();
    __builtin_amdgcn_s_setprio(1);
#pragma unroll
    for (int m = 0; m < 4; ++m)
#pragma unroll
      for (int n = 0; n < 4; ++n)
        acc[m][n] = __builtin_amdgcn_mfma_f32_16x16x32_bf16(af[m], bf[n], acc[m][n], 0, 0, 0);
    __builtin_amdgcn_s_setprio(0);
    SPIN();
    SBAR();
    if (t + 1 == T1) { SPIN(); epi(0); }
    c = cnext;
  }
  epi(1);
}

// ---------------------------------------------------------------------------
extern "C" void kernel_launch(void* const* d_in, const int* in_sizes, int n_in,
                              void* d_out, int out_size, void* d_ws, size_t ws_size,
                              hipStream_t stream) {
  const float* x  = (const float*)d_in[0];
  const float* Wq = (const float*)d_in[1];
  const float* bq = (const float*)d_in[2];
  const float* Wk = (const float*)d_in[3];
  const float* bk = (const float*)d_in[4];
  const float* Wv = (const float*)d_in[5];
  const float* bv = (const float*)d_in[6];
  const float* Wo = (const float*)d_in[7];
  const float* bo = (const float*)d_in[8];

  const int S = 4096, D = 1024;
  const size_t XE = (size_t)4 * S * D;
  const size_t BSE = (size_t)S * D;

  char* ws = (char*)d_ws;
  u16* xb  = (u16*)(ws + 0);                     // [16384,1024]; dead after proj -> vT
  u16* q   = (u16*)(ws + 33554432);
  u16* k   = (u16*)(ws + 67108864);
  u16* v   = (u16*)(ws + 100663296);             // dead after transpose -> attn3
  u16* ctx = (u16*)(ws + 134217728);
  u16* wqT = (u16*)(ws + 167772160);
  u16* wkT = wqT + 1048576;
  u16* wvT = wkT + 1048576;
  u16* woT = wvT + 1048576;
  u16* attn2 = (u16*)(ws + 176160768);           // [4096,4096] bf16
  u16* attn0 = (u16*)d_out;                      // d_out 67MB, dead until out-proj
  u16* attn1 = attn0 + (size_t)S * S;
  u16* attn3 = v;
  u16* vT = xb;                                  // [1024,4096] per batch, contiguous
  u16* attn[4] = {attn0, attn1, attn2, attn3};
  // softmax scratch: gM/gS live in ctx region (consumed by sm_combine before
  // PV writes ctx); Mrow/Linv in dead wqT region (persists through PV).
  float* gM   = (float*)(ws + 134217728);        // [4][16][4096] f32 = 1 MB
  float* gS   = gM + (size_t)4 * 16 * 4096;      // 1 MB
  float* Mrow = (float*)(ws + 167772160);        // [4][4096] f32 = 64 KB
  float* LinvP = Mrow + (size_t)4 * 4096;        // 64 KB

  // 1. cast x -> bf16
  cast_f32_bf16<<<(int)(XE / 4 / 256), 256, 0, stream>>>(x, xb, (int)(XE / 4));
  // 2. weight transposes (NOTE: wqT overlaps Mrow/Linv only AFTER proj is done)
  {
    TransPtrs tp = {{Wq, Wk, Wv, Wo}, {wqT, wkT, wvT, woT}};
    transpose_to_bf16<true><<<dim3(32, 32, 4), dim3(32, 8), 0, stream>>>(tp, D, D);
  }
  // 3. q/k/v projections: 768 tiles = 256 blocks x 3 slots (z = slot)
  {
    GemmPtrs gp = {{xb, xb, xb, xb}, {wqT, wkT, wvT, wqT},
                   {bq, bk, bv, bq}, {q, k, v, q}};
    gemm8ph<0, true, true><<<256, 512, 0, stream>>>(gp, D, 1.0f, nullptr, nullptr);
  }
  // 4. v -> v^T per batch (overwrites dead xb)
  {
    TransPtrs tp = {{v, v + BSE, v + 2 * BSE, v + 3 * BSE},
                    {vT, vT + BSE, vT + 2 * BSE, vT + 3 * BSE}};
    transpose_to_bf16<false><<<dim3(D / 32, S / 32, 4), dim3(32, 8), 0, stream>>>(tp, S, D);
  }
  // 5. scores = (q k^T)*scale + softmax partials: 544 tri tiles
  {
    GemmPtrs gp = {{q, q + BSE, q + 2 * BSE, q + 3 * BSE},
                   {k, k + BSE, k + 2 * BSE, k + 3 * BSE},
                   {nullptr, nullptr, nullptr, nullptr},
                   {attn[0], attn[1], attn[2], attn[3]}};
    gemm8ph<1, true, false><<<256, 512, 0, stream>>>(gp, S, 0.03125f, gM, gS);
  }
  // 6. combine partials -> per-row M, 1/L (writes into dead wqT region)
  sm_combine<<<64, 256, 0, stream>>>(gM, gS, Mrow, LinvP);
  // 7. ctx = softmax(attn) @ v fused: 256 blocks x 132 K-tiles (balanced)
  {
    GemmPtrs gp = {{attn[0], attn[1], attn[2], attn[3]},
                   {vT, vT + BSE, vT + 2 * BSE, vT + 3 * BSE},
                   {nullptr, nullptr, nullptr, nullptr},
                   {ctx, ctx + BSE, ctx + 2 * BSE, ctx + 3 * BSE}};
    gemm_pvf<<<256, 512, 0, stream>>>(gp, Mrow, LinvP);
  }
  // 8. out = ctx Wo^T + bo (fp32 -> d_out)
  {
    GemmPtrs gp = {{ctx, ctx, ctx, ctx}, {woT, woT, woT, woT},
                   {bo, bo, bo, bo}, {d_out, d_out, d_out, d_out}};
    gemm8ph<3, false, true><<<256, 512, 0, stream>>>(gp, D, 1.0f, nullptr, nullptr);
  }
}

// Round 8
// 553.096 us; speedup vs baseline: 1.3111x; 1.3111x over previous
//
#include <hip/hip_runtime.h>

// ---------------------------------------------------------------------------
// StandAttention: out = softmax_causal((xWq+bq)(xWk+bk)^T / sqrt(d)) (xWv+bv) Wo + bo
// b=4, s=4096, d=1024. fp32 in/out, bf16 MFMA compute.
//
// R14 = revert to R12 (best verified 508us; R13's double-fusion regressed to
// 725us and is abandoned) + ONE lever: scores load-balance.
//  - MODE1 was 4 blocks/XCD x 3 slots (96 K-tiles) vs 28 x 2 (64): dispatch
//    runs at the 96-tile critical path. Now: every block 2 full slots; the 32
//    leftover tiles K-split in half across 8 blocks/XCD as a 16-K-tile
//    half-slot writing raw f32 partials into scratch (ctx region, dead until
//    PV). reduce_half sums halves -> bf16 attn (~5us). Critical path 96->80.
//  - gemm8ph core loop, gemm_pv3, softmax, transposes: byte-identical to R12.
// ---------------------------------------------------------------------------

typedef unsigned short u16;
typedef __attribute__((ext_vector_type(4))) unsigned short u16x4;
typedef __attribute__((ext_vector_type(8))) unsigned short u16x8;
typedef __attribute__((ext_vector_type(8))) __bf16 bf16x8;
typedef __attribute__((ext_vector_type(4))) float f32x4;

typedef const __attribute__((address_space(1))) void* as1cp;
typedef __attribute__((address_space(3))) void* as3p;

#define SBAR() __builtin_amdgcn_s_barrier()
#define SPIN() __builtin_amdgcn_sched_barrier(0)

struct GemmPtrs {
  const u16* A[4];
  const u16* B[4];
  const float* bias[4];
  void* C[4];
};
struct TransPtrs {
  const void* in[4];
  u16* out[4];
};
struct SmPtrs {
  u16* P[4];
};

__device__ __forceinline__ u16 f2bf(float f) {
  union { float f; unsigned int i; } c; c.f = f;
  unsigned int r = c.i + 0x7fffu + ((c.i >> 16) & 1u);   // RNE
  return (u16)(r >> 16);
}
__device__ __forceinline__ float bf2f(u16 u) {
  union { unsigned int i; float f; } c; c.i = ((unsigned int)u) << 16;
  return c.f;
}

// ---------------- cast fp32 -> bf16 (vectorized) ----------------
__global__ __launch_bounds__(256) void cast_f32_bf16(const float* __restrict__ in,
                                                     u16* __restrict__ out, int n4) {
  int i = blockIdx.x * blockDim.x + threadIdx.x;
  if (i >= n4) return;
  float4 v = ((const float4*)in)[i];
  u16x4 u;
  u.x = f2bf(v.x); u.y = f2bf(v.y); u.z = f2bf(v.z); u.w = f2bf(v.w);
  ((u16x4*)out)[i] = u;
}

// ---------------- LDS-tiled transpose (-> bf16), batched by z ----------------
template <bool IN_F32>
__global__ __launch_bounds__(256) void transpose_to_bf16(TransPtrs tp, int R, int C) {
  __shared__ u16 t[32][34];
  int z = blockIdx.z;
  int tx = threadIdx.x, ty = threadIdx.y;
  int c0 = blockIdx.x * 32, r0 = blockIdx.y * 32;
#pragma unroll
  for (int dy = 0; dy < 4; ++dy) {
    int r = r0 + ty + dy * 8;
    int c = c0 + tx;
    u16 hv;
    if (IN_F32) hv = f2bf(((const float*)tp.in[z])[(size_t)r * C + c]);
    else        hv = ((const u16*)tp.in[z])[(size_t)r * C + c];
    t[ty + dy * 8][tx] = hv;
  }
  __syncthreads();
  u16* op = tp.out[z];
#pragma unroll
  for (int dy = 0; dy < 4; ++dy) {
    int a = ty + dy * 8;
    op[(size_t)(c0 + a) * R + r0 + tx] = t[tx][a];
  }
}

// ---------------- causal softmax, in-place, trimmed to j<=row ----------------
__global__ __launch_bounds__(256) void softmax_causal(SmPtrs sp) {
  int row = blockIdx.x;
  u16* P = sp.P[blockIdx.y];
  int tid = threadIdx.x;
  int lane = tid & 63, wv = tid >> 6;
  u16x8* prow = (u16x8*)(P + (size_t)row * 4096);
  int nch = (row >> 3) + 1;           // vec8 chunks containing any j<=row
  int fend = ((row >> 7) + 1) << 4;   // chunks to the 128 boundary PV reads
  int c0 = tid, c1 = tid + 256;
  bool a0 = c0 < nch, a1 = c1 < nch;
  float vals[16];
  float lmax = -3.0e38f;
  if (a0) {
    u16x8 u = prow[c0];
#pragma unroll
    for (int e = 0; e < 8; ++e) {
      float f = (c0 * 8 + e <= row) ? bf2f(u[e]) : -3.0e38f;
      vals[e] = f; lmax = fmaxf(lmax, f);
    }
  } else {
#pragma unroll
    for (int e = 0; e < 8; ++e) vals[e] = -3.0e38f;
  }
  if (a1) {
    u16x8 u = prow[c1];
#pragma unroll
    for (int e = 0; e < 8; ++e) {
      float f = (c1 * 8 + e <= row) ? bf2f(u[e]) : -3.0e38f;
      vals[8 + e] = f; lmax = fmaxf(lmax, f);
    }
  } else {
#pragma unroll
    for (int e = 0; e < 8; ++e) vals[8 + e] = -3.0e38f;
  }
  __shared__ float red[8];
#pragma unroll
  for (int off = 32; off > 0; off >>= 1) lmax = fmaxf(lmax, __shfl_down(lmax, off, 64));
  if (lane == 0) red[wv] = lmax;
  __syncthreads();
  float m2 = fmaxf(fmaxf(red[0], red[1]), fmaxf(red[2], red[3]));
  float lsum = 0.f;
#pragma unroll
  for (int e = 0; e < 16; ++e) {
    float ev = __expf(vals[e] - m2);
    vals[e] = ev;
    lsum += ev;
  }
#pragma unroll
  for (int off = 32; off > 0; off >>= 1) lsum += __shfl_down(lsum, off, 64);
  if (lane == 0) red[4 + wv] = lsum;
  __syncthreads();
  float inv = 1.0f / (red[4] + red[5] + red[6] + red[7]);
  if (a0) {
    u16x8 u;
#pragma unroll
    for (int e = 0; e < 8; ++e) u[e] = f2bf(vals[e] * inv);
    prow[c0] = u;
  }
  if (a1) {
    u16x8 u;
#pragma unroll
    for (int e = 0; e < 8; ++e) u[e] = f2bf(vals[8 + e] * inv);
    prow[c1] = u;
  }
  u16x8 zz = (u16x8)(u16)0;
  for (int c = nch + tid; c < fend; c += 256) prow[c] = zz;
}

// ---------------- reduce K-split partials -> bf16 attn tiles ----------------
// part: [64][256][256] f32 (32 tiles x 2 K-halves). 32 tiles = x in [0,8) x
// e in [0,4), tile id g = x*68 + 64 + e in the global tri order.
__global__ __launch_bounds__(256) void reduce_half(const float* __restrict__ part,
                                                   SmPtrs sp, float scale) {
  int idx = blockIdx.x * 256 + threadIdx.x;   // 0 .. 524287 (x4 elems)
  int tile = idx >> 14;                       // 16384 vec4 per tile
  int e4 = idx & 16383;
  int r = e4 >> 6, c4 = (e4 & 63) << 2;
  int x = tile >> 2, e = tile & 3;
  int g = x * 68 + 64 + e;
  int z = g / 136, L = g - z * 136;
  int i = (int)((__fsqrt_rn(8.f * (float)L + 1.f) - 1.f) * 0.5f);
  while ((i + 1) * (i + 2) / 2 <= L) ++i;
  while (i * (i + 1) / 2 > L) --i;
  int j = L - ((i * (i + 1)) >> 1);
  const float* p0 = part + ((size_t)tile * 2) * 65536 + r * 256 + c4;
  f32x4 a = *(const f32x4*)p0;
  f32x4 b = *(const f32x4*)(p0 + 65536);
  u16x4 o;
#pragma unroll
  for (int q = 0; q < 4; ++q) o[q] = f2bf((a[q] + b[q]) * scale);
  *(u16x4*)(sp.P[z] + (size_t)(i * 256 + r) * 4096 + j * 256 + c4) = o;
}

// ---------------------------------------------------------------------------
// gemm8ph: 256x256 tile, BK=32, 8 waves (2M x 4N), per-wave 128x64 out.
// Ring-3 LDS. Per K-tile: 2 phases {read frags | stage half of t+2 | SBAR |
// lgkm(0) | 16 MFMA | SBAR}; vmcnt(4) once per K-tile. (R12-proven core.)
// MODE 0: q/k/v proj (3 slots)  MODE 1: scores, 2 full slots + K-split
// half-slot (16 K-tiles, f32 partial) on 8 blocks/XCD  MODE 3: out-proj.
// ---------------------------------------------------------------------------
template <int MODE, bool OUT_BF16, bool HAS_BIAS>
__global__ __launch_bounds__(512, 2) void gemm8ph(GemmPtrs p, int N, float cscale,
                                                  float* gPart) {
  __shared__ __align__(16) u16 As[3][8192];   // ring x 256 rows x 32 k
  __shared__ __align__(16) u16 Bs[3][8192];
  const int b = blockIdx.x;
  const int tid = threadIdx.x, lane = tid & 63, wv = tid >> 6;
  const int wm = (wv >> 2) << 7, wn = (wv & 3) << 6;
  const int lrow = lane & 15, lquad = lane >> 4;
  const int xs = (lquad ^ ((lrow >> 1) & 3)) << 3;
  const int aoff0 = (wm + lrow) * 32 + xs;
  const int boff0 = (wn + lrow) * 32 + xs;
  // stage src pre-swizzle: LDS[r][c] = G[r][c ^ ((r>>1)&3)]  (0 conflicts)
  const int soff = (tid >> 2) * 1024 + (((tid & 3) ^ ((tid >> 3) & 3)) << 3);
  const int x = b & 7, u = b >> 3;            // XCD, index-on-XCD
  const int nslot = (MODE == 1) ? (u < 8 ? 3 : 2) : (MODE == 0 ? 3 : 1);
  const int T = (MODE == 1) ? (u < 8 ? 80 : 64) : (MODE == 0 ? 96 : 32);

  struct TP { const u16* A; const u16* B; int tm, tn, z; };
  auto tileOf = [&](int s) {
    TP t;
    if (MODE == 0) {
      int i = x * 32 + u;                 // 8-row band per XCD, reused over 3 mats
      t.z = s; t.tm = (i >> 2) << 8; t.tn = (i & 3) << 8;
      t.A = p.A[t.z] + (size_t)t.tm * 1024;
      t.B = p.B[t.z] + (size_t)t.tn * 1024;
    } else if (MODE == 1) {
      int g, kh = 0;
      if (s < 2) g = x * 68 + s * 32 + u;   // per-XCD contiguous tri range
      else { g = x * 68 + 64 + (u >> 1); kh = u & 1; }
      t.z = g / 136; int L = g - t.z * 136;
      int i = (int)((__fsqrt_rn(8.f * (float)L + 1.f) - 1.f) * 0.5f);
      while ((i + 1) * (i + 2) / 2 <= L) ++i;
      while (i * (i + 1) / 2 > L) --i;
      t.tm = i << 8; t.tn = (L - ((i * (i + 1)) >> 1)) << 8;
      t.A = p.A[t.z] + (size_t)t.tm * 1024 + kh * 512;
      t.B = p.B[t.z] + (size_t)t.tn * 1024 + kh * 512;
    } else {
      int i = x * 32 + u;
      t.z = 0; t.tm = (i >> 2) << 8; t.tn = (i & 3) << 8;
      t.A = p.A[t.z] + (size_t)t.tm * 1024;
      t.B = p.B[t.z] + (size_t)t.tn * 1024;
    }
    return t;
  };

  // staging cursor (2 K-tiles ahead of compute)
  const u16* gA; const u16* gB; int stk = 0, sslot = 0;
  {
    TP t0 = tileOf(0);
    gA = t0.A + soff; gB = t0.B + soff;
  }
  auto adv = [&]() {
    gA += 32; gB += 32;
    const int nit = (MODE == 1 && sslot == 2) ? 16 : 32;
    if (++stk == nit) {
      stk = 0;
      if (++sslot < nslot) {
        TP t = tileOf(sslot);
        gA = t.A + soff; gB = t.B + soff;
      }
    }
  };
  auto stgA = [&](int s) __attribute__((always_inline)) {
    __builtin_amdgcn_global_load_lds((as1cp)gA, (as3p)(As[s] + wv * 512), 16, 0, 0);
    __builtin_amdgcn_global_load_lds((as1cp)(gA + 131072), (as3p)(As[s] + 4096 + wv * 512), 16, 0, 0);
  };
  auto stgB = [&](int s) __attribute__((always_inline)) {
    __builtin_amdgcn_global_load_lds((as1cp)gB, (as3p)(Bs[s] + wv * 512), 16, 0, 0);
    __builtin_amdgcn_global_load_lds((as1cp)(gB + 131072), (as3p)(Bs[s] + 4096 + wv * 512), 16, 0, 0);
    adv();
  };

  f32x4 acc[8][4];
#pragma unroll
  for (int i = 0; i < 8; ++i)
#pragma unroll
    for (int j = 0; j < 4; ++j) acc[i][j] = (f32x4){0.f, 0.f, 0.f, 0.f};

  auto epi = [&](int cs2) {
    TP t = tileOf(cs2);
    if (MODE == 1 && cs2 == 2) {
      // K-split half-slot: raw f32 partial -> scratch (scale applied in reduce)
      float* dst = gPart + ((size_t)((x * 4 + (u >> 1)) * 2 + (u & 1))) * 65536;
#pragma unroll
      for (int m = 0; m < 8; ++m)
#pragma unroll
        for (int r = 0; r < 4; ++r) {
          int row = wm + m * 16 + lquad * 4 + r;
#pragma unroll
          for (int n = 0; n < 4; ++n)
            dst[row * 256 + wn + n * 16 + lrow] = acc[m][n][r];
        }
    } else {
      float bvv[4] = {0.f, 0.f, 0.f, 0.f};
      if constexpr (HAS_BIAS) {
#pragma unroll
        for (int n = 0; n < 4; ++n) bvv[n] = p.bias[t.z][t.tn + wn + n * 16 + lrow];
      }
#pragma unroll
      for (int m = 0; m < 8; ++m)
#pragma unroll
        for (int r = 0; r < 4; ++r) {
          size_t row = (size_t)(t.tm + wm + m * 16 + lquad * 4 + r);
#pragma unroll
          for (int n = 0; n < 4; ++n) {
            int col = t.tn + wn + n * 16 + lrow;
            float vvv = acc[m][n][r] * cscale + bvv[n];
            if (OUT_BF16) ((u16*)p.C[t.z])[row * N + col] = f2bf(vvv);
            else          ((float*)p.C[t.z])[row * N + col] = vvv;
          }
        }
    }
#pragma unroll
    for (int m2 = 0; m2 < 8; ++m2)
#pragma unroll
      for (int n2 = 0; n2 < 4; ++n2) acc[m2][n2] = (f32x4){0.f, 0.f, 0.f, 0.f};
  };

  // prologue: stage tiles 0,1 -> slots 0,1; publish tile 0 (tile 1 in flight)
  stgA(0); stgB(0);
  stgA(1); stgB(1);
  asm volatile("s_waitcnt vmcnt(4)");
  SBAR();
  SPIN();

  int cs = 0, c = 0, kend = 32;
  for (int t = 0; t < T; ++t) {
    const int s = (c >= 1) ? c - 1 : 2;       // (c+2)%3
    const bool stg = (t + 2) < T;
    bf16x8 af[4], bf[4];
    // ---------------- phase 0: m0-3 x n0-3 ----------------
#pragma unroll
    for (int m = 0; m < 4; ++m) af[m] = *(const bf16x8*)&As[c][aoff0 + m * 512];
#pragma unroll
    for (int n = 0; n < 4; ++n) bf[n] = *(const bf16x8*)&Bs[c][boff0 + n * 512];
    if (stg) stgA(s);
    SPIN();
    SBAR();
    asm volatile("s_waitcnt lgkmcnt(0)");
    SPIN();
    __builtin_amdgcn_s_setprio(1);
#pragma unroll
    for (int m = 0; m < 4; ++m)
#pragma unroll
      for (int n = 0; n < 4; ++n)
        acc[m][n] = __builtin_amdgcn_mfma_f32_16x16x32_bf16(af[m], bf[n], acc[m][n], 0, 0, 0);
    __builtin_amdgcn_s_setprio(0);
    SPIN();
    SBAR();
    // ---------------- phase 1: m4-7 x n0-3 (B held) ----------------
#pragma unroll
    for (int m = 0; m < 4; ++m) af[m] = *(const bf16x8*)&As[c][aoff0 + 2048 + m * 512];
    if (stg) stgB(s);
    SPIN();
    if (stg)               asm volatile("s_waitcnt vmcnt(4)");
    else if (t + 1 < T)    asm volatile("s_waitcnt vmcnt(0)");
    SBAR();
    asm volatile("s_waitcnt lgkmcnt(0)");
    SPIN();
    __builtin_amdgcn_s_setprio(1);
#pragma unroll
    for (int m = 0; m < 4; ++m)
#pragma unroll
      for (int n = 0; n < 4; ++n)
        acc[4 + m][n] = __builtin_amdgcn_mfma_f32_16x16x32_bf16(af[m], bf[n], acc[4 + m][n], 0, 0, 0);
    __builtin_amdgcn_s_setprio(0);
    SPIN();
    SBAR();
    if (t + 1 == kend) {
      SPIN();
      epi(cs);
      ++cs;
      kend += (MODE == 1 && cs == 2) ? 16 : 32;
    }
    if (++c == 3) c = 0;
  }
}

// ---------------------------------------------------------------------------
// gemm_pv3: ctx[tile 128x256] = attn[128,K] @ vT[256,K]^T, K=128(i+1) causal.
// BK=32. Pair (i,31-i): every block exactly 132 K-tiles. Ring-3 (72KB).
// Per K-tile: {read A m0-3 + B n0-3 | stage t+2 (3 gloads) | vmcnt(3) | SBAR |
// lgkm(0) | 16 MFMA | SBAR}. (R12 unchanged.)
// ---------------------------------------------------------------------------
__global__ __launch_bounds__(512, 2) void gemm_pv3(GemmPtrs p) {
  __shared__ __align__(16) u16 As[3][4096];   // 128 x 32
  __shared__ __align__(16) u16 Bs[3][8192];   // 256 x 32
  const int b = blockIdx.x;
  const int tid = threadIdx.x, lane = tid & 63, wv = tid >> 6;
  const int wm = (wv >> 2) << 6, wn = (wv & 3) << 6;
  const int lrow = lane & 15, lquad = lane >> 4;
  const int xs = (lquad ^ ((lrow >> 1) & 3)) << 3;
  const int aoff0 = (wm + lrow) * 32 + xs;
  const int boff0 = (wn + lrow) * 32 + xs;
  const int soff = (tid >> 2) * 4096 + (((tid & 3) ^ ((tid >> 3) & 3)) << 3);
  const int x = b & 7, u = b >> 3;
  const int P = x * 32 + u;                   // n fastest within XCD (A reuse x4)
  const int z = P >> 6, j = (P >> 2) & 15, n4 = P & 3;
  const int i1 = j, i2 = 31 - j;
  const int tn = n4 << 8;
  const int T1 = (i1 + 1) * 4;
  const int niter1 = (i2 + 1) * 4;
  const u16* Abase = p.A[z];
  const u16* Bbase = p.B[z] + (size_t)tn * 4096;

  const u16* gA = Abase + (size_t)(i1 << 7) * 4096 + soff;
  const u16* gB = Bbase + soff;
  int stk = 0, sslot = 0;
  auto adv = [&]() {
    gA += 32; gB += 32;
    ++stk;
    if (sslot == 0 && stk == T1) {
      stk = 0; sslot = 1;
      gA = Abase + (size_t)(i2 << 7) * 4096 + soff;
      gB = Bbase + soff;
    } else if (sslot == 1 && stk == niter1) {
      stk = 0; sslot = 2;
    }
  };
  auto stage = [&](int s) __attribute__((always_inline)) {
    __builtin_amdgcn_global_load_lds((as1cp)gA, (as3p)(As[s] + wv * 512), 16, 0, 0);
    __builtin_amdgcn_global_load_lds((as1cp)gB, (as3p)(Bs[s] + wv * 512), 16, 0, 0);
    __builtin_amdgcn_global_load_lds((as1cp)(gB + 524288), (as3p)(Bs[s] + 4096 + wv * 512), 16, 0, 0);
    adv();
  };

  f32x4 acc[4][4];
#pragma unroll
  for (int i = 0; i < 4; ++i)
#pragma unroll
    for (int jj = 0; jj < 4; ++jj) acc[i][jj] = (f32x4){0.f, 0.f, 0.f, 0.f};

  auto epi = [&](int s) {
    int tm = (s ? i2 : i1) << 7;
#pragma unroll
    for (int m = 0; m < 4; ++m)
#pragma unroll
      for (int r = 0; r < 4; ++r) {
        size_t row = (size_t)(tm + wm + m * 16 + lquad * 4 + r);
#pragma unroll
        for (int n = 0; n < 4; ++n) {
          int col = tn + wn + n * 16 + lrow;
          ((u16*)p.C[z])[row * 1024 + col] = f2bf(acc[m][n][r]);
        }
      }
#pragma unroll
    for (int m2 = 0; m2 < 4; ++m2)
#pragma unroll
      for (int n2 = 0; n2 < 4; ++n2) acc[m2][n2] = (f32x4){0.f, 0.f, 0.f, 0.f};
  };

  // prologue: stage tiles 0,1; publish tile 0 (tile 1's 3 in flight)
  stage(0); stage(1);
  asm volatile("s_waitcnt vmcnt(3)");
  SBAR();
  SPIN();

  const int T = 132;
  int c = 0;
  for (int t = 0; t < T; ++t) {
    const int s = (c >= 1) ? c - 1 : 2;       // (c+2)%3
    const bool stg = (t + 2) < T;
    bf16x8 af[4], bf[4];
#pragma unroll
    for (int m = 0; m < 4; ++m) af[m] = *(const bf16x8*)&As[c][aoff0 + m * 512];
#pragma unroll
    for (int n = 0; n < 4; ++n) bf[n] = *(const bf16x8*)&Bs[c][boff0 + n * 512];
    if (stg) stage(s);
    SPIN();
    if (stg)            asm volatile("s_waitcnt vmcnt(3)");
    else if (t + 1 < T) asm volatile("s_waitcnt vmcnt(0)");
    SBAR();
    asm volatile("s_waitcnt lgkmcnt(0)");
    SPIN();
    __builtin_amdgcn_s_setprio(1);
#pragma unroll
    for (int m = 0; m < 4; ++m)
#pragma unroll
      for (int n = 0; n < 4; ++n)
        acc[m][n] = __builtin_amdgcn_mfma_f32_16x16x32_bf16(af[m], bf[n], acc[m][n], 0, 0, 0);
    __builtin_amdgcn_s_setprio(0);
    SPIN();
    SBAR();
    if (t + 1 == T1) { SPIN(); epi(0); }
    if (++c == 3) c = 0;
  }
  epi(1);
}

// ---------------------------------------------------------------------------
extern "C" void kernel_launch(void* const* d_in, const int* in_sizes, int n_in,
                              void* d_out, int out_size, void* d_ws, size_t ws_size,
                              hipStream_t stream) {
  const float* x  = (const float*)d_in[0];
  const float* Wq = (const float*)d_in[1];
  const float* bq = (const float*)d_in[2];
  const float* Wk = (const float*)d_in[3];
  const float* bk = (const float*)d_in[4];
  const float* Wv = (const float*)d_in[5];
  const float* bv = (const float*)d_in[6];
  const float* Wo = (const float*)d_in[7];
  const float* bo = (const float*)d_in[8];

  const int S = 4096, D = 1024;
  const size_t XE = (size_t)4 * S * D;
  const size_t BSE = (size_t)S * D;

  char* ws = (char*)d_ws;
  u16* xb  = (u16*)(ws + 0);                     // [16384,1024]; dead after proj -> vT
  u16* q   = (u16*)(ws + 33554432);
  u16* k   = (u16*)(ws + 67108864);
  u16* v   = (u16*)(ws + 100663296);             // dead after transpose -> attn3
  u16* ctx = (u16*)(ws + 134217728);
  u16* wqT = (u16*)(ws + 167772160);
  u16* wkT = wqT + 1048576;
  u16* wvT = wkT + 1048576;
  u16* woT = wvT + 1048576;
  u16* attn2 = (u16*)(ws + 176160768);           // [4096,4096] bf16
  u16* attn0 = (u16*)d_out;                      // d_out 67MB, dead until out-proj
  u16* attn1 = attn0 + (size_t)S * S;
  u16* attn3 = v;
  u16* vT = xb;                                  // [1024,4096] per batch, contiguous
  u16* attn[4] = {attn0, attn1, attn2, attn3};
  // K-split partial scratch: 64 x 256 x 256 f32 = 16MB in ctx region (ctx is
  // written only by PV, which runs after reduce_half consumed the partials).
  float* gPart = (float*)(ws + 134217728);

  // 1. cast x -> bf16
  cast_f32_bf16<<<(int)(XE / 4 / 256), 256, 0, stream>>>(x, xb, (int)(XE / 4));
  // 2. weight transposes
  {
    TransPtrs tp = {{Wq, Wk, Wv, Wo}, {wqT, wkT, wvT, woT}};
    transpose_to_bf16<true><<<dim3(32, 32, 4), dim3(32, 8), 0, stream>>>(tp, D, D);
  }
  // 3. q/k/v projections: 768 tiles = 256 blocks x 3 slots (z = slot)
  {
    GemmPtrs gp = {{xb, xb, xb, xb}, {wqT, wkT, wvT, wqT},
                   {bq, bk, bv, bq}, {q, k, v, q}};
    gemm8ph<0, true, true><<<256, 512, 0, stream>>>(gp, D, 1.0f, nullptr);
  }
  // 4. v -> v^T per batch (overwrites dead xb)
  {
    TransPtrs tp = {{v, v + BSE, v + 2 * BSE, v + 3 * BSE},
                    {vT, vT + BSE, vT + 2 * BSE, vT + 3 * BSE}};
    transpose_to_bf16<false><<<dim3(D / 32, S / 32, 4), dim3(32, 8), 0, stream>>>(tp, S, D);
  }
  // 5. scores = (q k^T)*scale: 512 full tiles + 32 K-split tiles (balanced 80)
  {
    GemmPtrs gp = {{q, q + BSE, q + 2 * BSE, q + 3 * BSE},
                   {k, k + BSE, k + 2 * BSE, k + 3 * BSE},
                   {nullptr, nullptr, nullptr, nullptr},
                   {attn[0], attn[1], attn[2], attn[3]}};
    gemm8ph<1, true, false><<<256, 512, 0, stream>>>(gp, S, 0.03125f, gPart);
  }
  // 5b. reduce K-split partials into attn (applies scale)
  {
    SmPtrs sp = {{attn[0], attn[1], attn[2], attn[3]}};
    reduce_half<<<2048, 256, 0, stream>>>(gPart, sp, 0.03125f);
  }
  // 6. causal softmax in-place (trimmed + fringe zeros)
  {
    SmPtrs sp = {{attn[0], attn[1], attn[2], attn[3]}};
    softmax_causal<<<dim3(S, 4), 256, 0, stream>>>(sp);
  }
  // 7. ctx = attn @ v: paired causal tiles, 256 blocks x 132 K-tiles (balanced)
  {
    GemmPtrs gp = {{attn[0], attn[1], attn[2], attn[3]},
                   {vT, vT + BSE, vT + 2 * BSE, vT + 3 * BSE},
                   {nullptr, nullptr, nullptr, nullptr},
                   {ctx, ctx + BSE, ctx + 2 * BSE, ctx + 3 * BSE}};
    gemm_pv3<<<256, 512, 0, stream>>>(gp);
  }
  // 8. out = ctx Wo^T + bo (fp32 -> d_out)
  {
    GemmPtrs gp = {{ctx, ctx, ctx, ctx}, {woT, woT, woT, woT},
                   {bo, bo, bo, bo}, {d_out, d_out, d_out, d_out}};
    gemm8ph<3, false, true><<<256, 512, 0, stream>>>(gp, D, 1.0f, nullptr);
  }
}